// Round 1
// baseline (754.758 us; speedup 1.0000x reference)
//
#include <hip/hip_runtime.h>

constexpr int PR  = 512;           // plane resolution
constexpr int CP  = 24;            // plane channels (OUT_DIM * RANK)
constexpr int FD  = 32;            // feature channels
constexpr int FR  = 128;           // feature resolution
constexpr int PSZ = PR * PR;

// ---------------------------------------------------------------------------
// Transpose 3 planes [24][512][512] -> ws [3][512][512][24] (channels innermost)
// Block = 256 threads handles half a row of one plane. Coalesced both ways via LDS.
// ---------------------------------------------------------------------------
__global__ __launch_bounds__(256) void transpose_planes(
    const float* __restrict__ p0, const float* __restrict__ p1,
    const float* __restrict__ p2, float* __restrict__ wsT)
{
    __shared__ float lds[CP][256];
    int b   = blockIdx.x;
    int p   = b >> 10;             // 1024 blocks per plane
    int rem = b & 1023;
    int y   = rem >> 1;
    int x0  = (rem & 1) << 8;
    const float* src = (p == 0) ? p0 : (p == 1) ? p1 : p2;
    int t = threadIdx.x;
    #pragma unroll
    for (int c = 0; c < CP; ++c)
        lds[c][t] = src[c * PSZ + y * PR + x0 + t];
    __syncthreads();
    float* dst = wsT + ((size_t)((p * PR + y) * PR + x0)) * CP;
    #pragma unroll
    for (int k = 0; k < CP; ++k) {
        int idx = k * 256 + t;
        dst[idx] = lds[idx % CP][idx / CP];
    }
}

// ---------------------------------------------------------------------------
// Main kernel: one thread per point.
//   TRANS=true : planes read from transposed ws layout with float4 loads
//   TRANS=false: fallback, reads original [C][H][W] layout with scalar loads
// ---------------------------------------------------------------------------
template <bool TRANS>
__global__ __launch_bounds__(256) void lrh_main(
    const float* __restrict__ pts,
    const float* __restrict__ P0, const float* __restrict__ P1,
    const float* __restrict__ P2,
    const float* __restrict__ wsT,
    const float* __restrict__ feat,
    float* __restrict__ out, int n)
{
    int i = blockIdx.x * blockDim.x + threadIdx.x;
    if (i >= n) return;

    float px = pts[3 * i + 0];
    float py = pts[3 * i + 1];
    float pz = pts[3 * i + 2];
    // plane combs: plane0 (x<-pt0, y<-pt1), plane1 (x<-pt0, y<-pt2), plane2 (x<-pt1, y<-pt2)
    float cx[3] = {px, px, py};
    float cy[3] = {py, pz, pz};

    int   o00[3], o01[3], o10[3], o11[3];
    float w00[3], w01[3], w10[3], w11[3];
    #pragma unroll
    for (int p = 0; p < 3; ++p) {
        float ux = (cx[p] + 1.0f) * 0.5f * (float)(PR - 1);
        float uy = (cy[p] + 1.0f) * 0.5f * (float)(PR - 1);
        float lx = floorf(ux), ly = floorf(uy);
        float fx = ux - lx,   fy = uy - ly;
        int jx = (int)lx, jy = (int)ly;
        float vx0 = (jx   >= 0 && jx   < PR) ? 1.f : 0.f;
        float vx1 = (jx+1 >= 0 && jx+1 < PR) ? 1.f : 0.f;
        float vy0 = (jy   >= 0 && jy   < PR) ? 1.f : 0.f;
        float vy1 = (jy+1 >= 0 && jy+1 < PR) ? 1.f : 0.f;
        float wx0 = (1.f - fx) * vx0, wx1 = fx * vx1;
        float wy0 = (1.f - fy) * vy0, wy1 = fy * vy1;
        int ix0 = min(max(jx,     0), PR - 1);
        int ix1 = min(max(jx + 1, 0), PR - 1);
        int iy0 = min(max(jy,     0), PR - 1);
        int iy1 = min(max(jy + 1, 0), PR - 1);
        w00[p] = wx0 * wy0; w01[p] = wx1 * wy0;
        w10[p] = wx0 * wy1; w11[p] = wx1 * wy1;
        if (TRANS) {
            o00[p] = (iy0 * PR + ix0) * CP; o01[p] = (iy0 * PR + ix1) * CP;
            o10[p] = (iy1 * PR + ix0) * CP; o11[p] = (iy1 * PR + ix1) * CP;
        } else {
            o00[p] = iy0 * PR + ix0; o01[p] = iy0 * PR + ix1;
            o10[p] = iy1 * PR + ix0; o11[p] = iy1 * PR + ix1;
        }
    }

    const float* TB[3];
    if (TRANS) {
        TB[0] = wsT;
        TB[1] = wsT + (size_t)PSZ * CP;
        TB[2] = wsT + (size_t)2 * PSZ * CP;
    } else {
        TB[0] = P0; TB[1] = P1; TB[2] = P2;
    }

    // rank-product reduction: interp[j] = sum_r  s0[j,r]*s1[j,r]*s2[j,r]
    float interp[3] = {0.f, 0.f, 0.f};
    #pragma unroll
    for (int cg = 0; cg < 6; ++cg) {       // 6 groups of 4 channels
        float pr[4] = {1.f, 1.f, 1.f, 1.f};
        #pragma unroll
        for (int p = 0; p < 3; ++p) {
            float s[4];
            if (TRANS) {
                const float4 a = *(const float4*)(TB[p] + o00[p] + cg * 4);
                const float4 b = *(const float4*)(TB[p] + o01[p] + cg * 4);
                const float4 c = *(const float4*)(TB[p] + o10[p] + cg * 4);
                const float4 d = *(const float4*)(TB[p] + o11[p] + cg * 4);
                s[0] = w00[p]*a.x + w01[p]*b.x + w10[p]*c.x + w11[p]*d.x;
                s[1] = w00[p]*a.y + w01[p]*b.y + w10[p]*c.y + w11[p]*d.y;
                s[2] = w00[p]*a.z + w01[p]*b.z + w10[p]*c.z + w11[p]*d.z;
                s[3] = w00[p]*a.w + w01[p]*b.w + w10[p]*c.w + w11[p]*d.w;
            } else {
                #pragma unroll
                for (int e = 0; e < 4; ++e) {
                    const float* B = TB[p] + (size_t)(cg * 4 + e) * PSZ;
                    s[e] = w00[p]*B[o00[p]] + w01[p]*B[o01[p]]
                         + w10[p]*B[o10[p]] + w11[p]*B[o11[p]];
                }
            }
            #pragma unroll
            for (int e = 0; e < 4; ++e) pr[e] *= s[e];
        }
        interp[cg >> 1] += (pr[0] + pr[1]) + (pr[2] + pr[3]);
    }

    // trilinear feature lookup: interp[0]->x (stride 1), [1]->y (128), [2]->z (16384)
    int   offc[8];
    float wc[8];
    {
        float fr[3], v0[3], v1[3];
        int i0c[3], i1c[3];
        #pragma unroll
        for (int k = 0; k < 3; ++k) {
            float uu = (interp[k] + 1.0f) * 0.5f * (float)(FR - 1);
            float lf = floorf(uu);
            fr[k] = uu - lf;
            int jj = (int)lf;
            v0[k] = (jj   >= 0 && jj   < FR) ? 1.f : 0.f;
            v1[k] = (jj+1 >= 0 && jj+1 < FR) ? 1.f : 0.f;
            i0c[k] = min(max(jj,     0), FR - 1);
            i1c[k] = min(max(jj + 1, 0), FR - 1);
        }
        #pragma unroll
        for (int m = 0; m < 8; ++m) {
            int bx = m & 1, by = (m >> 1) & 1, bz = m >> 2;
            int xi = bx ? i1c[0] : i0c[0];
            int yi = by ? i1c[1] : i0c[1];
            int zi = bz ? i1c[2] : i0c[2];
            float wx = bx ? fr[0] * v1[0] : (1.f - fr[0]) * v0[0];
            float wy = by ? fr[1] * v1[1] : (1.f - fr[1]) * v0[1];
            float wz = bz ? fr[2] * v1[2] : (1.f - fr[2]) * v0[2];
            offc[m] = zi * FR * FR + yi * FR + xi;
            wc[m]   = wx * wy * wz;
        }
    }

    float* outp = out + (size_t)i * FD;
    #pragma unroll
    for (int c4 = 0; c4 < FD / 4; ++c4) {
        float r[4];
        #pragma unroll
        for (int e = 0; e < 4; ++e) {
            const float* Fc = feat + (size_t)(c4 * 4 + e) * (FR * FR * FR);
            float v = 0.f;
            #pragma unroll
            for (int m = 0; m < 8; ++m) v = fmaf(wc[m], Fc[offc[m]], v);
            r[e] = v;
        }
        *(float4*)(outp + c4 * 4) = make_float4(r[0], r[1], r[2], r[3]);
    }
}

extern "C" void kernel_launch(void* const* d_in, const int* in_sizes, int n_in,
                              void* d_out, int out_size, void* d_ws, size_t ws_size,
                              hipStream_t stream) {
    const float* pts  = (const float*)d_in[0];
    const float* p0   = (const float*)d_in[1];
    const float* p1   = (const float*)d_in[2];
    const float* p2   = (const float*)d_in[3];
    const float* feat = (const float*)d_in[4];
    float* out = (float*)d_out;
    int n = in_sizes[0] / 3;

    const size_t need = (size_t)3 * PSZ * CP * sizeof(float);  // 75.5 MB
    bool use_trans = (d_ws != nullptr) && (ws_size >= need);

    int blocks = (n + 255) / 256;
    if (use_trans) {
        transpose_planes<<<3 * 1024, 256, 0, stream>>>(p0, p1, p2, (float*)d_ws);
        lrh_main<true><<<blocks, 256, 0, stream>>>(
            pts, p0, p1, p2, (const float*)d_ws, feat, out, n);
    } else {
        lrh_main<false><<<blocks, 256, 0, stream>>>(
            pts, p0, p1, p2, nullptr, feat, out, n);
    }
}